// Round 6
// baseline (620.417 us; speedup 1.0000x reference)
//
#include <hip/hip_runtime.h>

// ---------------------------------------------------------------------------
// 3-layer GraphSAGE (mean aggr, root weight) on MI355X.
//   per layer: out = mean_{j->i}(x_j) @ Wl + bl + x_i @ Wr   (+relu / +L2norm)
// R5 (resubmit; R5 bench never acquired a GPU):
//     (a) feature-sliced z/w ([8][N][16] bf16) + slice-pinned-to-XCD agg:
//     per-XCD gather working set 25.6MB -> 3.2MB (fits 4MB L2).
//     (b) full-width GEMM blocks: A row-tile fetched once, not 4x.
// ---------------------------------------------------------------------------

#define BSHIFT 9                 // 512 nodes per bucket
#define BNODES (1 << BSHIFT)
#define ROUND_LOG 12             // 4096 edges per partition round

typedef __attribute__((ext_vector_type(8))) short bf16x8;
typedef __attribute__((ext_vector_type(4))) float f32x4;
typedef __attribute__((ext_vector_type(8))) unsigned short u16x8;

__device__ inline float bf2f(unsigned short u) {
  unsigned v = ((unsigned)u) << 16;
  return __builtin_bit_cast(float, v);
}
__device__ inline unsigned short f2bf(float f) {
  unsigned u = __builtin_bit_cast(unsigned, f);
  u += 0x7FFF + ((u >> 16) & 1);  // round-to-nearest-even
  return (unsigned short)(u >> 16);
}

// ------------------------- casts -------------------------------------------

__global__ __launch_bounds__(256) void cast_x_kernel(
    const float* __restrict__ in, unsigned short* __restrict__ out, int n8) {
  for (int i = blockIdx.x * 256 + threadIdx.x; i < n8; i += gridDim.x * 256) {
    float4 a = *(const float4*)(in + (size_t)i * 8);
    float4 b = *(const float4*)(in + (size_t)i * 8 + 4);
    u16x8 o;
    o[0] = f2bf(a.x); o[1] = f2bf(a.y); o[2] = f2bf(a.z); o[3] = f2bf(a.w);
    o[4] = f2bf(b.x); o[5] = f2bf(b.y); o[6] = f2bf(b.z); o[7] = f2bf(b.w);
    *(u16x8*)(out + (size_t)i * 8) = o;
  }
}

// Wl[K][M], Wr[K][M] fp32 -> BT[2M][K] bf16 (rows 0..M-1 = Wl^T, M.. = Wr^T)
__global__ __launch_bounds__(256) void wtcast2_kernel(
    const float* __restrict__ Wl, const float* __restrict__ Wr,
    unsigned short* __restrict__ BT, int K, int M) {
  const int total = 2 * M * K;
  for (int i = blockIdx.x * 256 + threadIdx.x; i < total;
       i += gridDim.x * 256) {
    int r = i / K, k = i - r * K;
    float v = (r < M) ? Wl[(size_t)k * M + r] : Wr[(size_t)k * M + (r - M)];
    BT[i] = f2bf(v);
  }
}

// ------------------------- CSR build ---------------------------------------

__global__ __launch_bounds__(256) void hist_kernel(const int* __restrict__ dst,
                                                   int E,
                                                   int* __restrict__ gcnt) {
  __shared__ int h[256];
  h[threadIdx.x] = 0;
  __syncthreads();
  for (int i = blockIdx.x * 256 + threadIdx.x; i < E; i += gridDim.x * 256)
    atomicAdd(&h[dst[i] >> BSHIFT], 1);
  __syncthreads();
  int v = h[threadIdx.x];
  if (v) atomicAdd(&gcnt[threadIdx.x], v);
}

__global__ __launch_bounds__(256) void bucket_scan_kernel(
    const int* __restrict__ gcnt, int NB, int* __restrict__ gbase,
    int* __restrict__ gcur, int* __restrict__ row_ptr, int N, int E) {
  __shared__ int sh[256];
  const int t = threadIdx.x;
  const int v = (t < NB) ? gcnt[t] : 0;
  sh[t] = v;
  __syncthreads();
  for (int d = 1; d < 256; d <<= 1) {
    int u = (t >= d) ? sh[t - d] : 0;
    __syncthreads();
    sh[t] += u;
    __syncthreads();
  }
  gbase[t] = sh[t] - v;
  gcur[t] = sh[t] - v;
  if (t == 0) row_ptr[N] = E;
}

// partition edges into bucket-grouped packed (local_dst<<17 | src) words
__global__ __launch_bounds__(256) void partition_kernel(
    const int* __restrict__ src, const int* __restrict__ dst, int E,
    int* __restrict__ gcur, unsigned int* __restrict__ pairs) {
  __shared__ int lcnt[256];
  __shared__ int lbase[256];
  const int t = threadIdx.x;
  const int nRounds = (E + (1 << ROUND_LOG) - 1) >> ROUND_LOG;
  for (int r = blockIdx.x; r < nRounds; r += gridDim.x) {
    const int base = r << ROUND_LOG;
    lcnt[t] = 0;
    __syncthreads();
    int pk[16];  // (bucket << 12) | local_pos ; -1 = inactive
#pragma unroll
    for (int j = 0; j < 16; ++j) {
      int idx = base + j * 256 + t;
      pk[j] = -1;
      if (idx < E) {
        int b = dst[idx] >> BSHIFT;
        int lp = atomicAdd(&lcnt[b], 1);
        pk[j] = (b << 12) | lp;
      }
    }
    __syncthreads();
    int c = lcnt[t];
    if (c > 0) lbase[t] = atomicAdd(&gcur[t], c);
    __syncthreads();
#pragma unroll
    for (int j = 0; j < 16; ++j) {
      if (pk[j] >= 0) {
        int idx = base + j * 256 + t;
        int b = pk[j] >> 12;
        int p = lbase[b] + (pk[j] & 0xFFF);
        pairs[p] = ((unsigned)(dst[idx] & (BNODES - 1)) << 17) |
                   (unsigned)src[idx];
      }
    }
    __syncthreads();
  }
}

__global__ __launch_bounds__(256) void bucket_csr_kernel(
    const unsigned int* __restrict__ pairs, const int* __restrict__ gbase,
    const int* __restrict__ gcnt, int N, int* __restrict__ row_ptr,
    int* __restrict__ csr) {
  const int b = blockIdx.x;
  const int t = threadIdx.x;
  const int nb0 = b << BSHIFT;
  __shared__ int ldeg[BNODES];
  __shared__ int lscan[256];
  __shared__ int lcur[BNODES];
  const int base = gbase[b];
  const int cnt = gcnt[b];
  ldeg[t] = 0;
  ldeg[t + 256] = 0;
  __syncthreads();
  for (int e = t; e < cnt; e += 256)
    atomicAdd(&ldeg[pairs[base + e] >> 17], 1);
  __syncthreads();
  const int s2 = ldeg[2 * t] + ldeg[2 * t + 1];
  lscan[t] = s2;
  __syncthreads();
  for (int d = 1; d < 256; d <<= 1) {
    int u = (t >= d) ? lscan[t - d] : 0;
    __syncthreads();
    lscan[t] += u;
    __syncthreads();
  }
  const int ex = lscan[t] - s2;
  const int o0 = base + ex;
  const int o1 = o0 + ldeg[2 * t];
  const int n0 = nb0 + 2 * t;
  if (n0 < N) row_ptr[n0] = o0;
  if (n0 + 1 < N) row_ptr[n0 + 1] = o1;
  lcur[2 * t] = o0;
  lcur[2 * t + 1] = o1;
  __syncthreads();
  for (int e = t; e < cnt; e += 256) {
    unsigned int p = pairs[base + e];
    int pos = atomicAdd(&lcur[p >> 17], 1);
    csr[pos] = (int)(p & 0x1FFFF);
  }
}

// ------------------------- MFMA dual GEMM (full width per block) ------------
// Z[N x MH] = A @ BT[0:MH]^T ; W[N x MH] = A @ BT[MH:2MH]^T + bias.
// A: [N][128] bf16. BT: [2*MH][128] bf16 (K contiguous).
// Block: 256 thr = 4 waves; tile 128 rows x 2*MH cols; BK=64.
// Wave (wr,wc): 64 rows x MH cols; wc==0 -> Z frags, wc==1 -> W frags.
// If SLICED: outputs stored [MH/16][N][16] (slice-major; frag == slice).

template <int MH, bool SLICED>
__global__ __launch_bounds__(256) void gemm_dual(
    const unsigned short* __restrict__ A, const unsigned short* __restrict__ BT,
    const float* __restrict__ bias, unsigned short* __restrict__ Zs,
    unsigned short* __restrict__ Ws, int N) {
  constexpr int MT = 2 * MH;
  constexpr int F = MH / 16;  // col frags per wave
  __shared__ unsigned short As[128][72];  // +8 pad
  __shared__ unsigned short Bs[MT][72];
  const int t = threadIdx.x;
  const int rb = blockIdx.x * 128;
  const int l = t & 63, wv = t >> 6;
  const int wr = wv >> 1, wc = wv & 1;
  const int lr = l & 15, kb = l >> 4;

  f32x4 acc[4][F];
#pragma unroll
  for (int fr = 0; fr < 4; ++fr)
#pragma unroll
    for (int fc = 0; fc < F; ++fc) acc[fr][fc] = (f32x4)(0.f);

  const int sr = t >> 3;        // staging row 0..31
  const int sc = (t & 7) * 8;   // staging col (elems)

  for (int kt = 0; kt < 128; kt += 64) {
#pragma unroll
    for (int i = 0; i < 4; ++i) {  // A tile: 128 rows x 64 k
      int r = i * 32 + sr;
      int grow = rb + r;
      uint4 v = make_uint4(0, 0, 0, 0);
      if (grow < N) v = *(const uint4*)(A + (size_t)grow * 128 + kt + sc);
      *(uint4*)&As[r][sc] = v;
    }
#pragma unroll
    for (int i = 0; i < MT / 32; ++i) {  // B tile: 2*MH rows x 64 k
      int r = i * 32 + sr;
      uint4 v = *(const uint4*)(BT + (size_t)r * 128 + kt + sc);
      *(uint4*)&Bs[r][sc] = v;
    }
    __syncthreads();
#pragma unroll
    for (int ks = 0; ks < 2; ++ks) {
      bf16x8 a[4], b[F];
#pragma unroll
      for (int fr = 0; fr < 4; ++fr)
        a[fr] = *(const bf16x8*)&As[wr * 64 + fr * 16 + lr][ks * 32 + kb * 8];
#pragma unroll
      for (int fc = 0; fc < F; ++fc)
        b[fc] = *(const bf16x8*)&Bs[wc * MH + fc * 16 + lr][ks * 32 + kb * 8];
#pragma unroll
      for (int fr = 0; fr < 4; ++fr)
#pragma unroll
        for (int fc = 0; fc < F; ++fc)
          acc[fr][fc] = __builtin_amdgcn_mfma_f32_16x16x32_bf16(
              a[fr], b[fc], acc[fr][fc], 0, 0, 0);
    }
    __syncthreads();
  }
  // epilogue: C/D map col=lane&15, row=(lane>>4)*4+reg [m89]; frag width 16 ==
  // slice width, so frag index fc IS the slice index.
  unsigned short* Cb = wc ? Ws : Zs;
#pragma unroll
  for (int fc = 0; fc < F; ++fc) {
    const int cm = fc * 16 + lr;  // col within matrix
    const float bv = wc ? bias[cm] : 0.f;
#pragma unroll
    for (int fr = 0; fr < 4; ++fr) {
      const int row0 = rb + wr * 64 + fr * 16 + kb * 4;
#pragma unroll
      for (int j = 0; j < 4; ++j) {
        const int row = row0 + j;
        if (row < N) {
          size_t idx = SLICED ? ((size_t)(fc * N + row) * 16 + lr)
                              : ((size_t)row * MH + cm);
          Cb[idx] = f2bf(acc[fr][fc][j] + bv);
        }
      }
    }
  }
}

// ------------------------- sliced aggregation (layers 1-2) ------------------
// out[node][s*16..+15] = relu(mean(z_s[nbrs]) + w_s[node]).
// slice = blockIdx.x & 7 -> pinned to one XCD by round-robin dispatch;
// per-XCD z working set = N*16*2B = 3.2MB -> L2-resident.
// 4 lanes/node x 4 feats; 64 nodes per 256-thread block.

__global__ __launch_bounds__(256) void agg_relu_sliced(
    const unsigned short* __restrict__ Zs, const unsigned short* __restrict__ Ws,
    const int* __restrict__ row_ptr, const int* __restrict__ csr,
    unsigned short* __restrict__ out, int N) {
  const int s = blockIdx.x & 7;
  const int grp = blockIdx.x >> 3;
  const int node = grp * 64 + (threadIdx.x >> 2);
  const int l4 = threadIdx.x & 3;
  if (node >= N) return;
  const int sB = row_ptr[node];
  const int e = row_ptr[node + 1];
  const unsigned short* zb = Zs + (size_t)s * N * 16 + l4 * 4;
  float a0[4] = {0, 0, 0, 0}, a1[4] = {0, 0, 0, 0};
  int i = sB;
  for (; i + 1 < e; i += 2) {
    uint2 v0 = *(const uint2*)(zb + (size_t)csr[i] * 16);
    uint2 v1 = *(const uint2*)(zb + (size_t)csr[i + 1] * 16);
    a0[0] += bf2f((unsigned short)v0.x);
    a0[1] += bf2f((unsigned short)(v0.x >> 16));
    a0[2] += bf2f((unsigned short)v0.y);
    a0[3] += bf2f((unsigned short)(v0.y >> 16));
    a1[0] += bf2f((unsigned short)v1.x);
    a1[1] += bf2f((unsigned short)(v1.x >> 16));
    a1[2] += bf2f((unsigned short)v1.y);
    a1[3] += bf2f((unsigned short)(v1.y >> 16));
  }
  if (i < e) {
    uint2 v0 = *(const uint2*)(zb + (size_t)csr[i] * 16);
    a0[0] += bf2f((unsigned short)v0.x);
    a0[1] += bf2f((unsigned short)(v0.x >> 16));
    a0[2] += bf2f((unsigned short)v0.y);
    a0[3] += bf2f((unsigned short)(v0.y >> 16));
  }
  const int d = e - sB;
  const float inv = 1.0f / (float)(d > 0 ? d : 1);
  uint2 wv = *(const uint2*)(Ws + ((size_t)s * N + node) * 16 + l4 * 4);
  float r0 = fmaxf(fmaf(a0[0] + a1[0], inv, bf2f((unsigned short)wv.x)), 0.f);
  float r1 =
      fmaxf(fmaf(a0[1] + a1[1], inv, bf2f((unsigned short)(wv.x >> 16))), 0.f);
  float r2 = fmaxf(fmaf(a0[2] + a1[2], inv, bf2f((unsigned short)wv.y)), 0.f);
  float r3 =
      fmaxf(fmaf(a0[3] + a1[3], inv, bf2f((unsigned short)(wv.y >> 16))), 0.f);
  uint2 o;
  o.x = (unsigned)f2bf(r0) | ((unsigned)f2bf(r1) << 16);
  o.y = (unsigned)f2bf(r2) | ((unsigned)f2bf(r3) << 16);
  *(uint2*)(out + (size_t)node * 128 + s * 16 + l4 * 4) = o;
}

// ------------------------- layer-3 agg + L2 normalize (row-major) -----------
// D=64: 8 lanes/node, 32 nodes/block, fp32 output.

__global__ __launch_bounds__(256) void agg_norm_bf16_64(
    const unsigned short* __restrict__ z, const unsigned short* __restrict__ w,
    const int* __restrict__ row_ptr, const int* __restrict__ csr,
    float* __restrict__ out, int N) {
  const int g = threadIdx.x >> 3;
  const int lane = threadIdx.x & 7;
  const int node = blockIdx.x * 32 + g;
  if (node >= N) return;
  const int s = row_ptr[node];
  const int e = row_ptr[node + 1];
  float a0[8] = {0, 0, 0, 0, 0, 0, 0, 0};
  float a1[8] = {0, 0, 0, 0, 0, 0, 0, 0};
  int i = s;
  for (; i + 1 < e; i += 2) {
    u16x8 v0 = *(const u16x8*)(z + (size_t)csr[i] * 64 + lane * 8);
    u16x8 v1 = *(const u16x8*)(z + (size_t)csr[i + 1] * 64 + lane * 8);
#pragma unroll
    for (int j = 0; j < 8; ++j) {
      a0[j] += bf2f(v0[j]);
      a1[j] += bf2f(v1[j]);
    }
  }
  if (i < e) {
    u16x8 v0 = *(const u16x8*)(z + (size_t)csr[i] * 64 + lane * 8);
#pragma unroll
    for (int j = 0; j < 8; ++j) a0[j] += bf2f(v0[j]);
  }
  const int d = e - s;
  const float inv = 1.0f / (float)(d > 0 ? d : 1);
  u16x8 wv = *(const u16x8*)(w + (size_t)node * 64 + lane * 8);
  float v[8];
  float n2 = 0.f;
#pragma unroll
  for (int j = 0; j < 8; ++j) {
    v[j] = fmaf(a0[j] + a1[j], inv, bf2f(wv[j]));
    n2 = fmaf(v[j], v[j], n2);
  }
  n2 += __shfl_xor(n2, 1);
  n2 += __shfl_xor(n2, 2);
  n2 += __shfl_xor(n2, 4);
  const float invn = 1.0f / fmaxf(sqrtf(n2), 1e-12f);
  float* op = out + (size_t)node * 64 + lane * 8;
  float4 o0 = make_float4(v[0] * invn, v[1] * invn, v[2] * invn, v[3] * invn);
  float4 o1 = make_float4(v[4] * invn, v[5] * invn, v[6] * invn, v[7] * invn);
  *(float4*)op = o0;
  *(float4*)(op + 4) = o1;
}

// ------------------------- launch ------------------------------------------

extern "C" void kernel_launch(void* const* d_in, const int* in_sizes, int n_in,
                              void* d_out, int out_size, void* d_ws,
                              size_t ws_size, hipStream_t stream) {
  const float* x   = (const float*)d_in[0];
  const int*   ei  = (const int*)d_in[1];
  const float* Wl1 = (const float*)d_in[2];
  const float* bl1 = (const float*)d_in[3];
  const float* Wr1 = (const float*)d_in[4];
  const float* Wl2 = (const float*)d_in[5];
  const float* bl2 = (const float*)d_in[6];
  const float* Wr2 = (const float*)d_in[7];
  const float* Wl3 = (const float*)d_in[8];
  const float* bl3 = (const float*)d_in[9];
  const float* Wr3 = (const float*)d_in[10];

  const int N = in_sizes[0] / 128;
  const int E = in_sizes[1] / 2;
  const int* src = ei;
  const int* dst = ei + E;
  const int NB = (N + BNODES - 1) >> BSHIFT;

  char* ws = (char*)d_ws;
  size_t off = 0;
  auto take = [&](size_t bytes) -> char* {
    char* p = ws + off;
    off += (bytes + 255) & ~(size_t)255;
    return p;
  };
  unsigned short* xb   = (unsigned short*)take((size_t)N * 128 * 2);
  unsigned short* h    = (unsigned short*)take((size_t)N * 128 * 2);
  unsigned short* z    = (unsigned short*)take((size_t)N * 128 * 2);
  unsigned short* w    = (unsigned short*)take((size_t)N * 128 * 2);
  unsigned short* BT1  = (unsigned short*)take(256 * 128 * 2);
  unsigned short* BT2  = (unsigned short*)take(256 * 128 * 2);
  unsigned short* BT3  = (unsigned short*)take(128 * 128 * 2);
  int*          row_ptr = (int*)take((size_t)(N + 1) * 4);
  int*          csr     = (int*)take((size_t)E * 4);
  unsigned int* pairs   = (unsigned int*)take((size_t)E * 4);
  int*          gcnt    = (int*)take(256 * 4);
  int*          gbase   = (int*)take(256 * 4);
  int*          gcur    = (int*)take(256 * 4);
  (void)ws_size;

  // --- CSR build (bucketed two-phase, packed pairs)
  hipMemsetAsync(gcnt, 0, 256 * 4, stream);
  hist_kernel<<<1024, 256, 0, stream>>>(dst, E, gcnt);
  bucket_scan_kernel<<<1, 256, 0, stream>>>(gcnt, NB, gbase, gcur, row_ptr, N, E);
  const int nRounds = (E + (1 << ROUND_LOG) - 1) >> ROUND_LOG;
  partition_kernel<<<nRounds, 256, 0, stream>>>(src, dst, E, gcur, pairs);
  bucket_csr_kernel<<<NB, 256, 0, stream>>>(pairs, gbase, gcnt, N, row_ptr, csr);

  // --- casts
  cast_x_kernel<<<2048, 256, 0, stream>>>(x, xb, N * 16);
  wtcast2_kernel<<<128, 256, 0, stream>>>(Wl1, Wr1, BT1, 128, 128);
  wtcast2_kernel<<<128, 256, 0, stream>>>(Wl2, Wr2, BT2, 128, 128);
  wtcast2_kernel<<<64, 256, 0, stream>>>(Wl3, Wr3, BT3, 128, 64);

  const dim3 blk(256);
  const int rowBlocks = (N + 127) / 128;
  const int aggSliced = ((N + 63) / 64) * 8;
  const int aggB64 = (N + 31) / 32;

  // --- layer 1
  gemm_dual<128, true><<<rowBlocks, blk, 0, stream>>>(xb, BT1, bl1, z, w, N);
  agg_relu_sliced<<<aggSliced, blk, 0, stream>>>(z, w, row_ptr, csr, h, N);
  // --- layer 2
  gemm_dual<128, true><<<rowBlocks, blk, 0, stream>>>(h, BT2, bl2, z, w, N);
  agg_relu_sliced<<<aggSliced, blk, 0, stream>>>(z, w, row_ptr, csr, h, N);
  // --- layer 3 (width 64, row-major) + L2 normalize
  gemm_dual<64, false><<<rowBlocks, blk, 0, stream>>>(h, BT3, bl3, z, w, N);
  agg_norm_bf16_64<<<aggB64, blk, 0, stream>>>(z, w, row_ptr, csr,
                                               (float*)d_out, N);
}

// Round 8
// 460.402 us; speedup vs baseline: 1.3476x; 1.3476x over previous
//
#include <hip/hip_runtime.h>

// ---------------------------------------------------------------------------
// 3-layer GraphSAGE (mean aggr, root weight) on MI355X.
//   per layer: out = mean_{j->i}(x_j) @ Wl + bl + x_i @ Wr   (+relu / +L2norm)
// R7 (resubmit; bench never acquired a GPU):
//     revert R6's sliced agg (request-rate-bound regression: 8x32B segments
//     vs 1x256B per edge). Row-major bf16 agg + 4-edge unroll. GEMM 128x128
//     tiles (36KB LDS, ~4 blk/CU), x-cast fused into gemm1 staging, single
//     weight-cast dispatch.
// ---------------------------------------------------------------------------

#define BSHIFT 9                 // 512 nodes per bucket
#define BNODES (1 << BSHIFT)
#define ROUND_LOG 12             // 4096 edges per partition round

typedef __attribute__((ext_vector_type(8))) short bf16x8;
typedef __attribute__((ext_vector_type(4))) float f32x4;
typedef __attribute__((ext_vector_type(8))) unsigned short u16x8;

__device__ inline float bf2f(unsigned short u) {
  unsigned v = ((unsigned)u) << 16;
  return __builtin_bit_cast(float, v);
}
__device__ inline unsigned short f2bf(float f) {
  unsigned u = __builtin_bit_cast(unsigned, f);
  u += 0x7FFF + ((u >> 16) & 1);  // round-to-nearest-even
  return (unsigned short)(u >> 16);
}

// ------------------------- weight casts (one dispatch) ----------------------
// Three segments: [2*128*128 | 2*128*128 | 2*64*128] -> BT buffers
// (rows 0..M-1 = Wl^T, rows M..2M-1 = Wr^T; K=128 contiguous per row).

__global__ __launch_bounds__(256) void wtcast_all_kernel(
    const float* __restrict__ Wl1, const float* __restrict__ Wr1,
    const float* __restrict__ Wl2, const float* __restrict__ Wr2,
    const float* __restrict__ Wl3, const float* __restrict__ Wr3,
    unsigned short* __restrict__ BT1, unsigned short* __restrict__ BT2,
    unsigned short* __restrict__ BT3) {
  const int K = 128;
  const int n12 = 2 * 128 * K;  // 32768
  const int n3 = 2 * 64 * K;    // 16384
  const int total = 2 * n12 + n3;
  for (int i = blockIdx.x * 256 + threadIdx.x; i < total;
       i += gridDim.x * 256) {
    const float *Wl, *Wr;
    unsigned short* BT;
    int j, M;
    if (i < n12) {
      Wl = Wl1; Wr = Wr1; BT = BT1; j = i; M = 128;
    } else if (i < 2 * n12) {
      Wl = Wl2; Wr = Wr2; BT = BT2; j = i - n12; M = 128;
    } else {
      Wl = Wl3; Wr = Wr3; BT = BT3; j = i - 2 * n12; M = 64;
    }
    int r = j / K, k = j - r * K;
    float v = (r < M) ? Wl[(size_t)k * M + r] : Wr[(size_t)k * M + (r - M)];
    BT[j] = f2bf(v);
  }
}

// ------------------------- CSR build ---------------------------------------

__global__ __launch_bounds__(256) void hist_kernel(const int* __restrict__ dst,
                                                   int E,
                                                   int* __restrict__ gcnt) {
  __shared__ int h[256];
  h[threadIdx.x] = 0;
  __syncthreads();
  for (int i = blockIdx.x * 256 + threadIdx.x; i < E; i += gridDim.x * 256)
    atomicAdd(&h[dst[i] >> BSHIFT], 1);
  __syncthreads();
  int v = h[threadIdx.x];
  if (v) atomicAdd(&gcnt[threadIdx.x], v);
}

__global__ __launch_bounds__(256) void bucket_scan_kernel(
    const int* __restrict__ gcnt, int NB, int* __restrict__ gbase,
    int* __restrict__ gcur, int* __restrict__ row_ptr, int N, int E) {
  __shared__ int sh[256];
  const int t = threadIdx.x;
  const int v = (t < NB) ? gcnt[t] : 0;
  sh[t] = v;
  __syncthreads();
  for (int d = 1; d < 256; d <<= 1) {
    int u = (t >= d) ? sh[t - d] : 0;
    __syncthreads();
    sh[t] += u;
    __syncthreads();
  }
  gbase[t] = sh[t] - v;
  gcur[t] = sh[t] - v;
  if (t == 0) row_ptr[N] = E;
}

// partition edges into bucket-grouped packed (local_dst<<17 | src) words
__global__ __launch_bounds__(256) void partition_kernel(
    const int* __restrict__ src, const int* __restrict__ dst, int E,
    int* __restrict__ gcur, unsigned int* __restrict__ pairs) {
  __shared__ int lcnt[256];
  __shared__ int lbase[256];
  const int t = threadIdx.x;
  const int nRounds = (E + (1 << ROUND_LOG) - 1) >> ROUND_LOG;
  for (int r = blockIdx.x; r < nRounds; r += gridDim.x) {
    const int base = r << ROUND_LOG;
    lcnt[t] = 0;
    __syncthreads();
    int pk[16];  // (bucket << 12) | local_pos ; -1 = inactive
#pragma unroll
    for (int j = 0; j < 16; ++j) {
      int idx = base + j * 256 + t;
      pk[j] = -1;
      if (idx < E) {
        int b = dst[idx] >> BSHIFT;
        int lp = atomicAdd(&lcnt[b], 1);
        pk[j] = (b << 12) | lp;
      }
    }
    __syncthreads();
    int c = lcnt[t];
    if (c > 0) lbase[t] = atomicAdd(&gcur[t], c);
    __syncthreads();
#pragma unroll
    for (int j = 0; j < 16; ++j) {
      if (pk[j] >= 0) {
        int idx = base + j * 256 + t;
        int b = pk[j] >> 12;
        int p = lbase[b] + (pk[j] & 0xFFF);
        pairs[p] = ((unsigned)(dst[idx] & (BNODES - 1)) << 17) |
                   (unsigned)src[idx];
      }
    }
    __syncthreads();
  }
}

__global__ __launch_bounds__(256) void bucket_csr_kernel(
    const unsigned int* __restrict__ pairs, const int* __restrict__ gbase,
    const int* __restrict__ gcnt, int N, int* __restrict__ row_ptr,
    int* __restrict__ csr) {
  const int b = blockIdx.x;
  const int t = threadIdx.x;
  const int nb0 = b << BSHIFT;
  __shared__ int ldeg[BNODES];
  __shared__ int lscan[256];
  __shared__ int lcur[BNODES];
  const int base = gbase[b];
  const int cnt = gcnt[b];
  ldeg[t] = 0;
  ldeg[t + 256] = 0;
  __syncthreads();
  for (int e = t; e < cnt; e += 256)
    atomicAdd(&ldeg[pairs[base + e] >> 17], 1);
  __syncthreads();
  const int s2 = ldeg[2 * t] + ldeg[2 * t + 1];
  lscan[t] = s2;
  __syncthreads();
  for (int d = 1; d < 256; d <<= 1) {
    int u = (t >= d) ? lscan[t - d] : 0;
    __syncthreads();
    lscan[t] += u;
    __syncthreads();
  }
  const int ex = lscan[t] - s2;
  const int o0 = base + ex;
  const int o1 = o0 + ldeg[2 * t];
  const int n0 = nb0 + 2 * t;
  if (n0 < N) row_ptr[n0] = o0;
  if (n0 + 1 < N) row_ptr[n0 + 1] = o1;
  lcur[2 * t] = o0;
  lcur[2 * t + 1] = o1;
  __syncthreads();
  for (int e = t; e < cnt; e += 256) {
    unsigned int p = pairs[base + e];
    int pos = atomicAdd(&lcur[p >> 17], 1);
    csr[pos] = (int)(p & 0x1FFFF);
  }
}

// ------------------------- MFMA dual GEMM (128x128 tile) --------------------
// grid = (2, rowBlocks): blockIdx.x selects matrix (0: Z=A@Wl, 1: W=A@Wr+b).
// A: [N][128] (fp32 if AFP32, else bf16). BT: [2*MH][128] bf16.
// Block: 256 thr = 4 waves (2x2). Wave: 64 rows x MH/2 cols.
// LDS 36KB (MH=128) -> ~4 blocks/CU. Outputs row-major bf16 [N][MH].

template <int MH, bool AFP32>
__global__ __launch_bounds__(256) void gemm_dual(
    const void* __restrict__ Av, const unsigned short* __restrict__ BT,
    const float* __restrict__ bias, unsigned short* __restrict__ Z,
    unsigned short* __restrict__ W, int N) {
  constexpr int F = MH / 32;  // col frags per wave
  __shared__ unsigned short As[128][72];  // +8 pad
  __shared__ unsigned short Bs[MH][72];
  const int t = threadIdx.x;
  const int mat = blockIdx.x;  // 0 -> Z (no bias), 1 -> W (+bias)
  const unsigned short* BTm = BT + (size_t)mat * MH * 128;
  unsigned short* C = mat ? W : Z;
  const int rb = blockIdx.y * 128;
  const int l = t & 63, wv = t >> 6;
  const int wr = wv >> 1, wc = wv & 1;  // 2x2 wave grid
  const int lr = l & 15, kb = l >> 4;

  f32x4 acc[4][F];
#pragma unroll
  for (int fr = 0; fr < 4; ++fr)
#pragma unroll
    for (int fc = 0; fc < F; ++fc) acc[fr][fc] = (f32x4)(0.f);

  const int sr = t >> 3;       // staging row 0..31
  const int sc = (t & 7) * 8;  // staging col (elems)

  for (int kt = 0; kt < 128; kt += 64) {
#pragma unroll
    for (int i = 0; i < 4; ++i) {  // A tile: 128 rows x 64 k
      int r = i * 32 + sr;
      int grow = rb + r;
      if constexpr (AFP32) {
        const float* Af = (const float*)Av;
        float4 v0 = make_float4(0.f, 0.f, 0.f, 0.f);
        float4 v1 = make_float4(0.f, 0.f, 0.f, 0.f);
        if (grow < N) {
          v0 = *(const float4*)(Af + (size_t)grow * 128 + kt + sc);
          v1 = *(const float4*)(Af + (size_t)grow * 128 + kt + sc + 4);
        }
        u16x8 o;
        o[0] = f2bf(v0.x); o[1] = f2bf(v0.y); o[2] = f2bf(v0.z);
        o[3] = f2bf(v0.w); o[4] = f2bf(v1.x); o[5] = f2bf(v1.y);
        o[6] = f2bf(v1.z); o[7] = f2bf(v1.w);
        *(u16x8*)&As[r][sc] = o;
      } else {
        const unsigned short* Ab = (const unsigned short*)Av;
        uint4 v = make_uint4(0, 0, 0, 0);
        if (grow < N) v = *(const uint4*)(Ab + (size_t)grow * 128 + kt + sc);
        *(uint4*)&As[r][sc] = v;
      }
    }
#pragma unroll
    for (int i = 0; i < MH / 32; ++i) {  // B tile: MH outcols x 64 k
      int r = i * 32 + sr;
      uint4 v = *(const uint4*)(BTm + (size_t)r * 128 + kt + sc);
      *(uint4*)&Bs[r][sc] = v;
    }
    __syncthreads();
#pragma unroll
    for (int ks = 0; ks < 2; ++ks) {
      bf16x8 a[4], b[F];
#pragma unroll
      for (int fr = 0; fr < 4; ++fr)
        a[fr] = *(const bf16x8*)&As[wr * 64 + fr * 16 + lr][ks * 32 + kb * 8];
#pragma unroll
      for (int fc = 0; fc < F; ++fc)
        b[fc] =
            *(const bf16x8*)&Bs[wc * (MH / 2) + fc * 16 + lr][ks * 32 + kb * 8];
#pragma unroll
      for (int fr = 0; fr < 4; ++fr)
#pragma unroll
        for (int fc = 0; fc < F; ++fc)
          acc[fr][fc] = __builtin_amdgcn_mfma_f32_16x16x32_bf16(
              a[fr], b[fc], acc[fr][fc], 0, 0, 0);
    }
    __syncthreads();
  }
  // epilogue: C/D map col=lane&15, row=(lane>>4)*4+reg [m89]
#pragma unroll
  for (int fc = 0; fc < F; ++fc) {
    const int cm = wc * (MH / 2) + fc * 16 + lr;
    const float bv = mat ? bias[cm] : 0.f;
#pragma unroll
    for (int fr = 0; fr < 4; ++fr) {
      const int row0 = rb + wr * 64 + fr * 16 + kb * 4;
#pragma unroll
      for (int j = 0; j < 4; ++j) {
        const int row = row0 + j;
        if (row < N) C[(size_t)row * MH + cm] = f2bf(acc[fr][fc][j] + bv);
      }
    }
  }
}

// ------------------------- aggregation (row-major bf16) ---------------------
// D=128: 16 lanes/node x 16B (8 bf16) -> one 256B segment per edge.
// 16 nodes per 256-thread block; 4-edge unroll for MLP.

__global__ __launch_bounds__(256) void agg_relu_bf16_128(
    const unsigned short* __restrict__ z, const unsigned short* __restrict__ w,
    const int* __restrict__ row_ptr, const int* __restrict__ csr,
    unsigned short* __restrict__ out, int N) {
  const int g = threadIdx.x >> 4;
  const int lane = threadIdx.x & 15;
  const int node = blockIdx.x * 16 + g;
  if (node >= N) return;
  const int s = row_ptr[node];
  const int e = row_ptr[node + 1];
  float a0[8] = {0, 0, 0, 0, 0, 0, 0, 0};
  float a1[8] = {0, 0, 0, 0, 0, 0, 0, 0};
  float a2[8] = {0, 0, 0, 0, 0, 0, 0, 0};
  float a3[8] = {0, 0, 0, 0, 0, 0, 0, 0};
  int i = s;
  for (; i + 3 < e; i += 4) {
    int s0 = csr[i], s1 = csr[i + 1], s2 = csr[i + 2], s3 = csr[i + 3];
    u16x8 v0 = *(const u16x8*)(z + (size_t)s0 * 128 + lane * 8);
    u16x8 v1 = *(const u16x8*)(z + (size_t)s1 * 128 + lane * 8);
    u16x8 v2 = *(const u16x8*)(z + (size_t)s2 * 128 + lane * 8);
    u16x8 v3 = *(const u16x8*)(z + (size_t)s3 * 128 + lane * 8);
#pragma unroll
    for (int j = 0; j < 8; ++j) {
      a0[j] += bf2f(v0[j]);
      a1[j] += bf2f(v1[j]);
      a2[j] += bf2f(v2[j]);
      a3[j] += bf2f(v3[j]);
    }
  }
  for (; i < e; ++i) {
    u16x8 v0 = *(const u16x8*)(z + (size_t)csr[i] * 128 + lane * 8);
#pragma unroll
    for (int j = 0; j < 8; ++j) a0[j] += bf2f(v0[j]);
  }
  const int d = e - s;
  const float inv = 1.0f / (float)(d > 0 ? d : 1);
  u16x8 wv = *(const u16x8*)(w + (size_t)node * 128 + lane * 8);
  u16x8 o;
#pragma unroll
  for (int j = 0; j < 8; ++j) {
    float sum = (a0[j] + a1[j]) + (a2[j] + a3[j]);
    o[j] = f2bf(fmaxf(fmaf(sum, inv, bf2f(wv[j])), 0.f));
  }
  *(u16x8*)(out + (size_t)node * 128 + lane * 8) = o;
}

// D=64 + L2 normalize: 8 lanes/node, 32 nodes/block, fp32 output.
__global__ __launch_bounds__(256) void agg_norm_bf16_64(
    const unsigned short* __restrict__ z, const unsigned short* __restrict__ w,
    const int* __restrict__ row_ptr, const int* __restrict__ csr,
    float* __restrict__ out, int N) {
  const int g = threadIdx.x >> 3;
  const int lane = threadIdx.x & 7;
  const int node = blockIdx.x * 32 + g;
  if (node >= N) return;
  const int s = row_ptr[node];
  const int e = row_ptr[node + 1];
  float a0[8] = {0, 0, 0, 0, 0, 0, 0, 0};
  float a1[8] = {0, 0, 0, 0, 0, 0, 0, 0};
  int i = s;
  for (; i + 1 < e; i += 2) {
    u16x8 v0 = *(const u16x8*)(z + (size_t)csr[i] * 64 + lane * 8);
    u16x8 v1 = *(const u16x8*)(z + (size_t)csr[i + 1] * 64 + lane * 8);
#pragma unroll
    for (int j = 0; j < 8; ++j) {
      a0[j] += bf2f(v0[j]);
      a1[j] += bf2f(v1[j]);
    }
  }
  if (i < e) {
    u16x8 v0 = *(const u16x8*)(z + (size_t)csr[i] * 64 + lane * 8);
#pragma unroll
    for (int j = 0; j < 8; ++j) a0[j] += bf2f(v0[j]);
  }
  const int d = e - s;
  const float inv = 1.0f / (float)(d > 0 ? d : 1);
  u16x8 wv = *(const u16x8*)(w + (size_t)node * 64 + lane * 8);
  float v[8];
  float n2 = 0.f;
#pragma unroll
  for (int j = 0; j < 8; ++j) {
    v[j] = fmaf(a0[j] + a1[j], inv, bf2f(wv[j]));
    n2 = fmaf(v[j], v[j], n2);
  }
  n2 += __shfl_xor(n2, 1);
  n2 += __shfl_xor(n2, 2);
  n2 += __shfl_xor(n2, 4);
  const float invn = 1.0f / fmaxf(sqrtf(n2), 1e-12f);
  float* op = out + (size_t)node * 64 + lane * 8;
  float4 o0 = make_float4(v[0] * invn, v[1] * invn, v[2] * invn, v[3] * invn);
  float4 o1 = make_float4(v[4] * invn, v[5] * invn, v[6] * invn, v[7] * invn);
  *(float4*)op = o0;
  *(float4*)(op + 4) = o1;
}

// ------------------------- launch ------------------------------------------

extern "C" void kernel_launch(void* const* d_in, const int* in_sizes, int n_in,
                              void* d_out, int out_size, void* d_ws,
                              size_t ws_size, hipStream_t stream) {
  const float* x   = (const float*)d_in[0];
  const int*   ei  = (const int*)d_in[1];
  const float* Wl1 = (const float*)d_in[2];
  const float* bl1 = (const float*)d_in[3];
  const float* Wr1 = (const float*)d_in[4];
  const float* Wl2 = (const float*)d_in[5];
  const float* bl2 = (const float*)d_in[6];
  const float* Wr2 = (const float*)d_in[7];
  const float* Wl3 = (const float*)d_in[8];
  const float* bl3 = (const float*)d_in[9];
  const float* Wr3 = (const float*)d_in[10];

  const int N = in_sizes[0] / 128;
  const int E = in_sizes[1] / 2;
  const int* src = ei;
  const int* dst = ei + E;
  const int NB = (N + BNODES - 1) >> BSHIFT;

  char* ws = (char*)d_ws;
  size_t off = 0;
  auto take = [&](size_t bytes) -> char* {
    char* p = ws + off;
    off += (bytes + 255) & ~(size_t)255;
    return p;
  };
  unsigned short* h    = (unsigned short*)take((size_t)N * 128 * 2);
  unsigned short* z    = (unsigned short*)take((size_t)N * 128 * 2);
  unsigned short* w    = (unsigned short*)take((size_t)N * 128 * 2);
  unsigned short* BT1  = (unsigned short*)take(256 * 128 * 2);
  unsigned short* BT2  = (unsigned short*)take(256 * 128 * 2);
  unsigned short* BT3  = (unsigned short*)take(128 * 128 * 2);
  int*          row_ptr = (int*)take((size_t)(N + 1) * 4);
  int*          csr     = (int*)take((size_t)E * 4);
  unsigned int* pairs   = (unsigned int*)take((size_t)E * 4);
  int*          gcnt    = (int*)take(256 * 4);
  int*          gbase   = (int*)take(256 * 4);
  int*          gcur    = (int*)take(256 * 4);
  (void)ws_size;

  // --- CSR build (bucketed two-phase, packed pairs)
  hipMemsetAsync(gcnt, 0, 256 * 4, stream);
  hist_kernel<<<1024, 256, 0, stream>>>(dst, E, gcnt);
  bucket_scan_kernel<<<1, 256, 0, stream>>>(gcnt, NB, gbase, gcur, row_ptr, N, E);
  const int nRounds = (E + (1 << ROUND_LOG) - 1) >> ROUND_LOG;
  partition_kernel<<<nRounds, 256, 0, stream>>>(src, dst, E, gcur, pairs);
  bucket_csr_kernel<<<NB, 256, 0, stream>>>(pairs, gbase, gcnt, N, row_ptr, csr);

  // --- weight casts (one dispatch)
  wtcast_all_kernel<<<320, 256, 0, stream>>>(Wl1, Wr1, Wl2, Wr2, Wl3, Wr3, BT1,
                                             BT2, BT3);

  const dim3 blk(256);
  const int rowBlocks = (N + 127) / 128;
  const dim3 gg(2, rowBlocks);
  const int aggB128 = (N + 15) / 16;
  const int aggB64  = (N + 31) / 32;

  // --- layer 1 (x fp32 read directly; cast fused into staging)
  gemm_dual<128, true><<<gg, blk, 0, stream>>>(x, BT1, bl1, z, w, N);
  agg_relu_bf16_128<<<aggB128, blk, 0, stream>>>(z, w, row_ptr, csr, h, N);
  // --- layer 2
  gemm_dual<128, false><<<gg, blk, 0, stream>>>(h, BT2, bl2, z, w, N);
  agg_relu_bf16_128<<<aggB128, blk, 0, stream>>>(z, w, row_ptr, csr, h, N);
  // --- layer 3 (width 64) + L2 normalize
  gemm_dual<64, false><<<gg, blk, 0, stream>>>(h, BT3, bl3, z, w, N);
  agg_norm_bf16_64<<<aggB64, blk, 0, stream>>>(z, w, row_ptr, csr,
                                               (float*)d_out, N);
}

// Round 9
// 411.374 us; speedup vs baseline: 1.5082x; 1.1192x over previous
//
#include <hip/hip_runtime.h>

// ---------------------------------------------------------------------------
// 3-layer GraphSAGE (mean aggr, root weight) on MI355X.
//   per layer: out = mean_{j->i}(x_j) @ Wl + bl + x_i @ Wr   (+relu / +L2norm)
// R9: fix GEMM epilogue write amplification (R8: 119MB written for 51MB of
//     output; per-lane 2B scattered bf16 stores dirtied partial 64B lines).
//     Now: stage C-tile in LDS (reuse As/Bs after last barrier), store
//     coalesced u16x8 full-line chunks.
// ---------------------------------------------------------------------------

#define BSHIFT 9                 // 512 nodes per bucket
#define BNODES (1 << BSHIFT)
#define ROUND_LOG 12             // 4096 edges per partition round

typedef __attribute__((ext_vector_type(8))) short bf16x8;
typedef __attribute__((ext_vector_type(4))) float f32x4;
typedef __attribute__((ext_vector_type(8))) unsigned short u16x8;

__device__ inline float bf2f(unsigned short u) {
  unsigned v = ((unsigned)u) << 16;
  return __builtin_bit_cast(float, v);
}
__device__ inline unsigned short f2bf(float f) {
  unsigned u = __builtin_bit_cast(unsigned, f);
  u += 0x7FFF + ((u >> 16) & 1);  // round-to-nearest-even
  return (unsigned short)(u >> 16);
}

// ------------------------- weight casts (one dispatch) ----------------------
// (rows 0..M-1 = Wl^T, rows M..2M-1 = Wr^T; K=128 contiguous per row).

__global__ __launch_bounds__(256) void wtcast_all_kernel(
    const float* __restrict__ Wl1, const float* __restrict__ Wr1,
    const float* __restrict__ Wl2, const float* __restrict__ Wr2,
    const float* __restrict__ Wl3, const float* __restrict__ Wr3,
    unsigned short* __restrict__ BT1, unsigned short* __restrict__ BT2,
    unsigned short* __restrict__ BT3) {
  const int K = 128;
  const int n12 = 2 * 128 * K;  // 32768
  const int n3 = 2 * 64 * K;    // 16384
  const int total = 2 * n12 + n3;
  for (int i = blockIdx.x * 256 + threadIdx.x; i < total;
       i += gridDim.x * 256) {
    const float *Wl, *Wr;
    unsigned short* BT;
    int j, M;
    if (i < n12) {
      Wl = Wl1; Wr = Wr1; BT = BT1; j = i; M = 128;
    } else if (i < 2 * n12) {
      Wl = Wl2; Wr = Wr2; BT = BT2; j = i - n12; M = 128;
    } else {
      Wl = Wl3; Wr = Wr3; BT = BT3; j = i - 2 * n12; M = 64;
    }
    int r = j / K, k = j - r * K;
    float v = (r < M) ? Wl[(size_t)k * M + r] : Wr[(size_t)k * M + (r - M)];
    BT[j] = f2bf(v);
  }
}

// ------------------------- CSR build ---------------------------------------

__global__ __launch_bounds__(256) void hist_kernel(const int* __restrict__ dst,
                                                   int E,
                                                   int* __restrict__ gcnt) {
  __shared__ int h[256];
  h[threadIdx.x] = 0;
  __syncthreads();
  for (int i = blockIdx.x * 256 + threadIdx.x; i < E; i += gridDim.x * 256)
    atomicAdd(&h[dst[i] >> BSHIFT], 1);
  __syncthreads();
  int v = h[threadIdx.x];
  if (v) atomicAdd(&gcnt[threadIdx.x], v);
}

__global__ __launch_bounds__(256) void bucket_scan_kernel(
    const int* __restrict__ gcnt, int NB, int* __restrict__ gbase,
    int* __restrict__ gcur, int* __restrict__ row_ptr, int N, int E) {
  __shared__ int sh[256];
  const int t = threadIdx.x;
  const int v = (t < NB) ? gcnt[t] : 0;
  sh[t] = v;
  __syncthreads();
  for (int d = 1; d < 256; d <<= 1) {
    int u = (t >= d) ? sh[t - d] : 0;
    __syncthreads();
    sh[t] += u;
    __syncthreads();
  }
  gbase[t] = sh[t] - v;
  gcur[t] = sh[t] - v;
  if (t == 0) row_ptr[N] = E;
}

// partition edges into bucket-grouped packed (local_dst<<17 | src) words
__global__ __launch_bounds__(256) void partition_kernel(
    const int* __restrict__ src, const int* __restrict__ dst, int E,
    int* __restrict__ gcur, unsigned int* __restrict__ pairs) {
  __shared__ int lcnt[256];
  __shared__ int lbase[256];
  const int t = threadIdx.x;
  const int nRounds = (E + (1 << ROUND_LOG) - 1) >> ROUND_LOG;
  for (int r = blockIdx.x; r < nRounds; r += gridDim.x) {
    const int base = r << ROUND_LOG;
    lcnt[t] = 0;
    __syncthreads();
    int pk[16];  // (bucket << 12) | local_pos ; -1 = inactive
#pragma unroll
    for (int j = 0; j < 16; ++j) {
      int idx = base + j * 256 + t;
      pk[j] = -1;
      if (idx < E) {
        int b = dst[idx] >> BSHIFT;
        int lp = atomicAdd(&lcnt[b], 1);
        pk[j] = (b << 12) | lp;
      }
    }
    __syncthreads();
    int c = lcnt[t];
    if (c > 0) lbase[t] = atomicAdd(&gcur[t], c);
    __syncthreads();
#pragma unroll
    for (int j = 0; j < 16; ++j) {
      if (pk[j] >= 0) {
        int idx = base + j * 256 + t;
        int b = pk[j] >> 12;
        int p = lbase[b] + (pk[j] & 0xFFF);
        pairs[p] = ((unsigned)(dst[idx] & (BNODES - 1)) << 17) |
                   (unsigned)src[idx];
      }
    }
    __syncthreads();
  }
}

__global__ __launch_bounds__(256) void bucket_csr_kernel(
    const unsigned int* __restrict__ pairs, const int* __restrict__ gbase,
    const int* __restrict__ gcnt, int N, int* __restrict__ row_ptr,
    int* __restrict__ csr) {
  const int b = blockIdx.x;
  const int t = threadIdx.x;
  const int nb0 = b << BSHIFT;
  __shared__ int ldeg[BNODES];
  __shared__ int lscan[256];
  __shared__ int lcur[BNODES];
  const int base = gbase[b];
  const int cnt = gcnt[b];
  ldeg[t] = 0;
  ldeg[t + 256] = 0;
  __syncthreads();
  for (int e = t; e < cnt; e += 256)
    atomicAdd(&ldeg[pairs[base + e] >> 17], 1);
  __syncthreads();
  const int s2 = ldeg[2 * t] + ldeg[2 * t + 1];
  lscan[t] = s2;
  __syncthreads();
  for (int d = 1; d < 256; d <<= 1) {
    int u = (t >= d) ? lscan[t - d] : 0;
    __syncthreads();
    lscan[t] += u;
    __syncthreads();
  }
  const int ex = lscan[t] - s2;
  const int o0 = base + ex;
  const int o1 = o0 + ldeg[2 * t];
  const int n0 = nb0 + 2 * t;
  if (n0 < N) row_ptr[n0] = o0;
  if (n0 + 1 < N) row_ptr[n0 + 1] = o1;
  lcur[2 * t] = o0;
  lcur[2 * t + 1] = o1;
  __syncthreads();
  for (int e = t; e < cnt; e += 256) {
    unsigned int p = pairs[base + e];
    int pos = atomicAdd(&lcur[p >> 17], 1);
    csr[pos] = (int)(p & 0x1FFFF);
  }
}

// ------------------------- MFMA dual GEMM (128x128 tile) --------------------
// grid = (2, rowBlocks): blockIdx.x selects matrix (0: Z=A@Wl, 1: W=A@Wr+b).
// A: [N][128] (fp32 if AFP32, else bf16). BT: [2*MH][128] bf16.
// Block: 256 thr = 4 waves (2x2). Wave: 64 rows x MH/2 cols.
// Epilogue: C-tile staged in LDS (aliases As/Bs), stored as coalesced u16x8.

template <int MH, bool AFP32>
__global__ __launch_bounds__(256) void gemm_dual(
    const void* __restrict__ Av, const unsigned short* __restrict__ BT,
    const float* __restrict__ bias, unsigned short* __restrict__ Z,
    unsigned short* __restrict__ W, int N) {
  constexpr int F = MH / 32;       // col frags per wave
  constexpr int CPAD = MH + 8;     // padded C-stage row (shorts)
  __shared__ unsigned short smem[128 * 72 + MH * 72];
  auto As = (unsigned short(*)[72])smem;
  auto Bs = (unsigned short(*)[72])(smem + 128 * 72);
  auto Cs = (unsigned short(*)[CPAD])smem;  // aliases As/Bs post-loop

  const int t = threadIdx.x;
  const int mat = blockIdx.x;  // 0 -> Z (no bias), 1 -> W (+bias)
  const unsigned short* BTm = BT + (size_t)mat * MH * 128;
  unsigned short* C = mat ? W : Z;
  const int rb = blockIdx.y * 128;
  const int l = t & 63, wv = t >> 6;
  const int wr = wv >> 1, wc = wv & 1;  // 2x2 wave grid
  const int lr = l & 15, kb = l >> 4;

  f32x4 acc[4][F];
#pragma unroll
  for (int fr = 0; fr < 4; ++fr)
#pragma unroll
    for (int fc = 0; fc < F; ++fc) acc[fr][fc] = (f32x4)(0.f);

  const int sr = t >> 3;       // staging row 0..31
  const int sc = (t & 7) * 8;  // staging col (elems)

  for (int kt = 0; kt < 128; kt += 64) {
#pragma unroll
    for (int i = 0; i < 4; ++i) {  // A tile: 128 rows x 64 k
      int r = i * 32 + sr;
      int grow = rb + r;
      if constexpr (AFP32) {
        const float* Af = (const float*)Av;
        float4 v0 = make_float4(0.f, 0.f, 0.f, 0.f);
        float4 v1 = make_float4(0.f, 0.f, 0.f, 0.f);
        if (grow < N) {
          v0 = *(const float4*)(Af + (size_t)grow * 128 + kt + sc);
          v1 = *(const float4*)(Af + (size_t)grow * 128 + kt + sc + 4);
        }
        u16x8 o;
        o[0] = f2bf(v0.x); o[1] = f2bf(v0.y); o[2] = f2bf(v0.z);
        o[3] = f2bf(v0.w); o[4] = f2bf(v1.x); o[5] = f2bf(v1.y);
        o[6] = f2bf(v1.z); o[7] = f2bf(v1.w);
        *(u16x8*)&As[r][sc] = o;
      } else {
        const unsigned short* Ab = (const unsigned short*)Av;
        uint4 v = make_uint4(0, 0, 0, 0);
        if (grow < N) v = *(const uint4*)(Ab + (size_t)grow * 128 + kt + sc);
        *(uint4*)&As[r][sc] = v;
      }
    }
#pragma unroll
    for (int i = 0; i < MH / 32; ++i) {  // B tile: MH outcols x 64 k
      int r = i * 32 + sr;
      uint4 v = *(const uint4*)(BTm + (size_t)r * 128 + kt + sc);
      *(uint4*)&Bs[r][sc] = v;
    }
    __syncthreads();
#pragma unroll
    for (int ks = 0; ks < 2; ++ks) {
      bf16x8 a[4], b[F];
#pragma unroll
      for (int fr = 0; fr < 4; ++fr)
        a[fr] = *(const bf16x8*)&As[wr * 64 + fr * 16 + lr][ks * 32 + kb * 8];
#pragma unroll
      for (int fc = 0; fc < F; ++fc)
        b[fc] =
            *(const bf16x8*)&Bs[wc * (MH / 2) + fc * 16 + lr][ks * 32 + kb * 8];
#pragma unroll
      for (int fr = 0; fr < 4; ++fr)
#pragma unroll
        for (int fc = 0; fc < F; ++fc)
          acc[fr][fc] = __builtin_amdgcn_mfma_f32_16x16x32_bf16(
              a[fr], b[fc], acc[fr][fc], 0, 0, 0);
    }
    __syncthreads();  // last iter: also guards Cs aliasing of As/Bs
  }

  // --- epilogue: frags -> LDS (C/D map col=lane&15, row=(lane>>4)*4+reg) ---
#pragma unroll
  for (int fc = 0; fc < F; ++fc) {
    const int cm = wc * (MH / 2) + fc * 16 + lr;
    const float bv = mat ? bias[cm] : 0.f;
#pragma unroll
    for (int fr = 0; fr < 4; ++fr) {
      const int r0 = wr * 64 + fr * 16 + kb * 4;
#pragma unroll
      for (int j = 0; j < 4; ++j) Cs[r0 + j][cm] = f2bf(acc[fr][fc][j] + bv);
    }
  }
  __syncthreads();
  // --- coalesced store: row = MH bf16 = MH*2 bytes, u16x8 chunks ---
  constexpr int CHUNKS = MH / 8;  // 16B chunks per row
  for (int idx = t; idx < 128 * CHUNKS; idx += 256) {
    int row = idx / CHUNKS, ch = idx - row * CHUNKS;
    int grow = rb + row;
    if (grow < N) {
      u16x8 v = *(const u16x8*)&Cs[row][ch * 8];
      *(u16x8*)&C[(size_t)grow * MH + ch * 8] = v;
    }
  }
}

// ------------------------- aggregation (row-major bf16) ---------------------
// D=128: 16 lanes/node x 16B (8 bf16) -> one 256B segment per edge.
// 16 nodes per 256-thread block; 4-edge unroll for MLP.

__global__ __launch_bounds__(256) void agg_relu_bf16_128(
    const unsigned short* __restrict__ z, const unsigned short* __restrict__ w,
    const int* __restrict__ row_ptr, const int* __restrict__ csr,
    unsigned short* __restrict__ out, int N) {
  const int g = threadIdx.x >> 4;
  const int lane = threadIdx.x & 15;
  const int node = blockIdx.x * 16 + g;
  if (node >= N) return;
  const int s = row_ptr[node];
  const int e = row_ptr[node + 1];
  float a0[8] = {0, 0, 0, 0, 0, 0, 0, 0};
  float a1[8] = {0, 0, 0, 0, 0, 0, 0, 0};
  float a2[8] = {0, 0, 0, 0, 0, 0, 0, 0};
  float a3[8] = {0, 0, 0, 0, 0, 0, 0, 0};
  int i = s;
  for (; i + 3 < e; i += 4) {
    int s0 = csr[i], s1 = csr[i + 1], s2 = csr[i + 2], s3 = csr[i + 3];
    u16x8 v0 = *(const u16x8*)(z + (size_t)s0 * 128 + lane * 8);
    u16x8 v1 = *(const u16x8*)(z + (size_t)s1 * 128 + lane * 8);
    u16x8 v2 = *(const u16x8*)(z + (size_t)s2 * 128 + lane * 8);
    u16x8 v3 = *(const u16x8*)(z + (size_t)s3 * 128 + lane * 8);
#pragma unroll
    for (int j = 0; j < 8; ++j) {
      a0[j] += bf2f(v0[j]);
      a1[j] += bf2f(v1[j]);
      a2[j] += bf2f(v2[j]);
      a3[j] += bf2f(v3[j]);
    }
  }
  for (; i < e; ++i) {
    u16x8 v0 = *(const u16x8*)(z + (size_t)csr[i] * 128 + lane * 8);
#pragma unroll
    for (int j = 0; j < 8; ++j) a0[j] += bf2f(v0[j]);
  }
  const int d = e - s;
  const float inv = 1.0f / (float)(d > 0 ? d : 1);
  u16x8 wv = *(const u16x8*)(w + (size_t)node * 128 + lane * 8);
  u16x8 o;
#pragma unroll
  for (int j = 0; j < 8; ++j) {
    float sum = (a0[j] + a1[j]) + (a2[j] + a3[j]);
    o[j] = f2bf(fmaxf(fmaf(sum, inv, bf2f(wv[j])), 0.f));
  }
  *(u16x8*)(out + (size_t)node * 128 + lane * 8) = o;
}

// D=64 + L2 normalize: 8 lanes/node, 32 nodes/block, fp32 output.
__global__ __launch_bounds__(256) void agg_norm_bf16_64(
    const unsigned short* __restrict__ z, const unsigned short* __restrict__ w,
    const int* __restrict__ row_ptr, const int* __restrict__ csr,
    float* __restrict__ out, int N) {
  const int g = threadIdx.x >> 3;
  const int lane = threadIdx.x & 7;
  const int node = blockIdx.x * 32 + g;
  if (node >= N) return;
  const int s = row_ptr[node];
  const int e = row_ptr[node + 1];
  float a0[8] = {0, 0, 0, 0, 0, 0, 0, 0};
  float a1[8] = {0, 0, 0, 0, 0, 0, 0, 0};
  int i = s;
  for (; i + 1 < e; i += 2) {
    u16x8 v0 = *(const u16x8*)(z + (size_t)csr[i] * 64 + lane * 8);
    u16x8 v1 = *(const u16x8*)(z + (size_t)csr[i + 1] * 64 + lane * 8);
#pragma unroll
    for (int j = 0; j < 8; ++j) {
      a0[j] += bf2f(v0[j]);
      a1[j] += bf2f(v1[j]);
    }
  }
  if (i < e) {
    u16x8 v0 = *(const u16x8*)(z + (size_t)csr[i] * 64 + lane * 8);
#pragma unroll
    for (int j = 0; j < 8; ++j) a0[j] += bf2f(v0[j]);
  }
  const int d = e - s;
  const float inv = 1.0f / (float)(d > 0 ? d : 1);
  u16x8 wv = *(const u16x8*)(w + (size_t)node * 64 + lane * 8);
  float v[8];
  float n2 = 0.f;
#pragma unroll
  for (int j = 0; j < 8; ++j) {
    v[j] = fmaf(a0[j] + a1[j], inv, bf2f(wv[j]));
    n2 = fmaf(v[j], v[j], n2);
  }
  n2 += __shfl_xor(n2, 1);
  n2 += __shfl_xor(n2, 2);
  n2 += __shfl_xor(n2, 4);
  const float invn = 1.0f / fmaxf(sqrtf(n2), 1e-12f);
  float* op = out + (size_t)node * 64 + lane * 8;
  float4 o0 = make_float4(v[0] * invn, v[1] * invn, v[2] * invn, v[3] * invn);
  float4 o1 = make_float4(v[4] * invn, v[5] * invn, v[6] * invn, v[7] * invn);
  *(float4*)op = o0;
  *(float4*)(op + 4) = o1;
}

// ------------------------- launch ------------------------------------------

extern "C" void kernel_launch(void* const* d_in, const int* in_sizes, int n_in,
                              void* d_out, int out_size, void* d_ws,
                              size_t ws_size, hipStream_t stream) {
  const float* x   = (const float*)d_in[0];
  const int*   ei  = (const int*)d_in[1];
  const float* Wl1 = (const float*)d_in[2];
  const float* bl1 = (const float*)d_in[3];
  const float* Wr1 = (const float*)d_in[4];
  const float* Wl2 = (const float*)d_in[5];
  const float* bl2 = (const float*)d_in[6];
  const float* Wr2 = (const float*)d_in[7];
  const float* Wl3 = (const float*)d_in[8];
  const float* bl3 = (const float*)d_in[9];
  const float* Wr3 = (const float*)d_in[10];

  const int N = in_sizes[0] / 128;
  const int E = in_sizes[1] / 2;
  const int* src = ei;
  const int* dst = ei + E;
  const int NB = (N + BNODES - 1) >> BSHIFT;

  char* ws = (char*)d_ws;
  size_t off = 0;
  auto take = [&](size_t bytes) -> char* {
    char* p = ws + off;
    off += (bytes + 255) & ~(size_t)255;
    return p;
  };
  unsigned short* h    = (unsigned short*)take((size_t)N * 128 * 2);
  unsigned short* z    = (unsigned short*)take((size_t)N * 128 * 2);
  unsigned short* w    = (unsigned short*)take((size_t)N * 128 * 2);
  unsigned short* BT1  = (unsigned short*)take(256 * 128 * 2);
  unsigned short* BT2  = (unsigned short*)take(256 * 128 * 2);
  unsigned short* BT3  = (unsigned short*)take(128 * 128 * 2);
  int*          row_ptr = (int*)take((size_t)(N + 1) * 4);
  int*          csr     = (int*)take((size_t)E * 4);
  unsigned int* pairs   = (unsigned int*)take((size_t)E * 4);
  int*          gcnt    = (int*)take(256 * 4);
  int*          gbase   = (int*)take(256 * 4);
  int*          gcur    = (int*)take(256 * 4);
  (void)ws_size;

  // --- CSR build (bucketed two-phase, packed pairs)
  hipMemsetAsync(gcnt, 0, 256 * 4, stream);
  hist_kernel<<<1024, 256, 0, stream>>>(dst, E, gcnt);
  bucket_scan_kernel<<<1, 256, 0, stream>>>(gcnt, NB, gbase, gcur, row_ptr, N, E);
  const int nRounds = (E + (1 << ROUND_LOG) - 1) >> ROUND_LOG;
  partition_kernel<<<nRounds, 256, 0, stream>>>(src, dst, E, gcur, pairs);
  bucket_csr_kernel<<<NB, 256, 0, stream>>>(pairs, gbase, gcnt, N, row_ptr, csr);

  // --- weight casts (one dispatch)
  wtcast_all_kernel<<<320, 256, 0, stream>>>(Wl1, Wr1, Wl2, Wr2, Wl3, Wr3, BT1,
                                             BT2, BT3);

  const dim3 blk(256);
  const int rowBlocks = (N + 127) / 128;
  const dim3 gg(2, rowBlocks);
  const int aggB128 = (N + 15) / 16;
  const int aggB64  = (N + 31) / 32;

  // --- layer 1 (x fp32 read directly; cast fused into staging)
  gemm_dual<128, true><<<gg, blk, 0, stream>>>(x, BT1, bl1, z, w, N);
  agg_relu_bf16_128<<<aggB128, blk, 0, stream>>>(z, w, row_ptr, csr, h, N);
  // --- layer 2
  gemm_dual<128, false><<<gg, blk, 0, stream>>>(h, BT2, bl2, z, w, N);
  agg_relu_bf16_128<<<aggB128, blk, 0, stream>>>(z, w, row_ptr, csr, h, N);
  // --- layer 3 (width 64) + L2 normalize
  gemm_dual<64, false><<<gg, blk, 0, stream>>>(h, BT3, bl3, z, w, N);
  agg_norm_bf16_64<<<aggB64, blk, 0, stream>>>(z, w, row_ptr, csr,
                                               (float*)d_out, N);
}